// Round 6
// baseline (495.848 us; speedup 1.0000x reference)
//
#include <hip/hip_runtime.h>
#include <cstdint>

// ---- problem constants (MoEFeedForward: N=4096, D=1024, F=2048, E=8, top-2) ----
#define N_TOK 4096
#define D_MODEL 1024
#define D_FF 2048
#define D_GU 4096          // 2*D_FF: gate_up col space; also GU row pitch
#define N_EXP 8

typedef __bf16 bf16;
typedef __bf16 bf16x8 __attribute__((ext_vector_type(8)));
typedef float f32x4 __attribute__((ext_vector_type(4)));

typedef __attribute__((address_space(1))) void v1_t;
typedef __attribute__((address_space(3))) void v3_t;

// async global->LDS raw copy, 16B/lane; dest = wave-uniform base + lane*16
__device__ __forceinline__ void cp16(void* lds, const void* g) {
  __builtin_amdgcn_global_load_lds((v1_t*)g, (v3_t*)lds, 16, 0, 0);
}

__device__ __forceinline__ f32x4 mfma16(bf16x8 a, bf16x8 b, f32x4 c) {
  return __builtin_amdgcn_mfma_f32_16x16x32_bf16(a, b, c, 0, 0, 0);
}

__device__ __forceinline__ bf16x8 cvt8(float4 a, float4 b) {
  bf16x8 v;
  v[0] = (bf16)a.x; v[1] = (bf16)a.y; v[2] = (bf16)a.z; v[3] = (bf16)a.w;
  v[4] = (bf16)b.x; v[5] = (bf16)b.y; v[6] = (bf16)b.z; v[7] = (bf16)b.w;
  return v;
}

// ======== router: logits -> softmax -> top2 -> per-token meta; fuses x fp32->bf16 ========
// No atomics: meta_e[t] = e0|(e1<<4); meta_p[t] = (p0,p1) renormalized.
__global__ __launch_bounds__(256) void router_kernel(
    const float* __restrict__ x, const float* __restrict__ wr,
    int* __restrict__ meta_e, float2* __restrict__ meta_p, bf16* __restrict__ xb)
{
  const int wave = threadIdx.x >> 6;
  const int lane = threadIdx.x & 63;

  for (int it = 0; it < 8; ++it) {
    const int token = blockIdx.x * 32 + it * 4 + wave;

    const float4* xrow = (const float4*)(x + (size_t)token * D_MODEL + lane * 16);
    float4 x0 = xrow[0], x1 = xrow[1], x2 = xrow[2], x3 = xrow[3];

    // side-product: bf16 copy of x (coalesced 16B stores)
    bf16* xd = xb + (size_t)token * D_MODEL + lane * 16;
    *(bf16x8*)xd       = cvt8(x0, x1);
    *(bf16x8*)(xd + 8) = cvt8(x2, x3);

    float logit[N_EXP];
#pragma unroll
    for (int e = 0; e < N_EXP; ++e) {
      const float4* wrow = (const float4*)(wr + e * D_MODEL + lane * 16);
      float4 w0 = wrow[0], w1 = wrow[1], w2 = wrow[2], w3 = wrow[3];
      float s = x0.x*w0.x + x0.y*w0.y + x0.z*w0.z + x0.w*w0.w
              + x1.x*w1.x + x1.y*w1.y + x1.z*w1.z + x1.w*w1.w
              + x2.x*w2.x + x2.y*w2.y + x2.z*w2.z + x2.w*w2.w
              + x3.x*w3.x + x3.y*w3.y + x3.z*w3.z + x3.w*w3.w;
#pragma unroll
      for (int m = 32; m >= 1; m >>= 1) s += __shfl_xor(s, m);
      logit[e] = fminf(fmaxf(s, -1e4f), 1e4f);    // reference CLAMP
    }

    if (lane == 0) {
      float mx = logit[0];
#pragma unroll
      for (int e = 1; e < N_EXP; ++e) mx = fmaxf(mx, logit[e]);
      float ex[N_EXP], sum = 0.f;
#pragma unroll
      for (int e = 0; e < N_EXP; ++e) { ex[e] = expf(logit[e] - mx); sum += ex[e]; }
      float p[N_EXP];
#pragma unroll
      for (int e = 0; e < N_EXP; ++e)
        p[e] = fminf(fmaxf(ex[e] / (sum + 1e-8f), 1e-8f), 1.0f);
      int e0 = 0;
#pragma unroll
      for (int e = 1; e < N_EXP; ++e) if (p[e] > p[e0]) e0 = e;
      int e1 = (e0 == 0) ? 1 : 0;
#pragma unroll
      for (int e = 0; e < N_EXP; ++e) if (e != e0 && p[e] > p[e1]) e1 = e;
      float p0 = p[e0], p1 = p[e1];
      float inv = 1.f / (p0 + p1 + 1e-8f);
      meta_e[token] = e0 | (e1 << 4);
      meta_p[token] = make_float2(p0 * inv, p1 * inv);
    }
  }
}

// ======== compact (block 0) + wgu fp32->bf16 cvt (blocks 1..) in ONE dispatch ========
// block 0: 8 waves, wave e ballot-scans meta over all tokens -> counts/offsets/ids/wts/tokslot
__global__ __launch_bounds__(512) void compact_cvt_kernel(
    const int* __restrict__ meta_e, const float2* __restrict__ meta_p,
    int* __restrict__ counts, int* __restrict__ offsets,
    int* __restrict__ ids, float* __restrict__ wts, int* __restrict__ tokslot,
    const float* __restrict__ wgu, bf16* __restrict__ wgub)
{
  if (blockIdx.x == 0) {
    __shared__ int lcnt[N_EXP], loff[N_EXP];
    const int wave = threadIdx.x >> 6;       // = expert e
    const int lane = threadIdx.x & 63;
    const int e = wave;
    // pass 1: count
    int c = 0;
    for (int ch = 0; ch < N_TOK / 64; ++ch) {
      int me = meta_e[ch * 64 + lane];
      bool pred = ((me & 15) == e) || (((me >> 4) & 15) == e);
      c += __popcll(__ballot(pred));
    }
    if (lane == 0) lcnt[e] = c;
    __syncthreads();
    if (threadIdx.x == 0) {
      int r = 0;
#pragma unroll
      for (int i = 0; i < N_EXP; ++i) {
        loff[i] = r; offsets[i] = r; counts[i] = lcnt[i]; r += lcnt[i];
      }
    }
    __syncthreads();
    // pass 2: assign slots
    const int goff = loff[e];
    int run = 0;
    for (int ch = 0; ch < N_TOK / 64; ++ch) {
      int t = ch * 64 + lane;
      int me = meta_e[t];
      bool is0 = ((me & 15) == e);
      bool pred = is0 || (((me >> 4) & 15) == e);
      unsigned long long mask = __ballot(pred);
      if (pred) {
        int li = run + __popcll(mask & ((1ull << lane) - 1ull));
        float2 p = meta_p[t];
        ids[e * N_TOK + li] = t;
        wts[e * N_TOK + li] = is0 ? p.x : p.y;
        tokslot[2 * t + (is0 ? 0 : 1)] = goff + li;
      }
      run += __popcll(mask);
    }
  } else {
    // wgu cvt: 32M elems = 4M bf16x8 items; 2048 blocks x 512 threads, 4 iters each
    const int n8 = (N_EXP * D_GU * D_MODEL) / 8;
    int i = (blockIdx.x - 1) * 512 + threadIdx.x;
    const int stride = (gridDim.x - 1) * 512;
    for (; i < n8; i += stride) {
      const float4* s = (const float4*)wgu + 2 * (size_t)i;
      ((bf16x8*)wgub)[i] = cvt8(s[0], s[1]);
    }
  }
}

// ====== GEMM1a: gathered xb @ Wgu_b^T -> GU bf16 (compacted rows, pitch 4096) ======
__global__ __launch_bounds__(256, 2) void gemm1a_kernel(
    const bf16* __restrict__ xb, const bf16* __restrict__ wgu,
    const int* __restrict__ counts, const int* __restrict__ offsets,
    const int* __restrict__ ids, bf16* __restrict__ GU)
{
  const int e = blockIdx.z;
  const int cnt = counts[e];
  const int row0 = blockIdx.y * 128;
  if (row0 >= cnt) return;
  const int c0 = blockIdx.x * 128;

  __shared__ bf16 lA[128 * 32];
  __shared__ bf16 lB[128 * 32];

  const int tid  = threadIdx.x;
  const int lane = tid & 63;
  const int wave = tid >> 6;
  const int l4 = lane >> 2;
  const int kb = (lane & 3) * 8;

  const int ra0 = wave * 16 + l4;
  const int ra1 = (wave + 4) * 16 + l4;

  const int* ide = ids + e * N_TOK;
  const int m0 = min(row0 + ra0, cnt - 1);
  const int m1 = min(row0 + ra1, cnt - 1);
  const bf16* srcA0 = xb + (size_t)ide[m0] * D_MODEL + kb;
  const bf16* srcA1 = xb + (size_t)ide[m1] * D_MODEL + kb;
  const bf16* wge = wgu + (size_t)e * D_GU * D_MODEL;
  const bf16* srcB0 = wge + (size_t)(c0 + ra0) * D_MODEL + kb;
  const bf16* srcB1 = wge + (size_t)(c0 + ra1) * D_MODEL + kb;

  char* dA0 = (char*)lA + wave * 1024;
  char* dA1 = (char*)lA + (wave + 4) * 1024;
  char* dB0 = (char*)lB + wave * 1024;
  char* dB1 = (char*)lB + (wave + 4) * 1024;

  const int wm = wave >> 1;
  const int wn = wave & 1;
  const int fr = lane & 15;
  const int fq = lane >> 4;
  const bf16* pA = lA + (wm * 64 + fr) * 32 + fq * 8;
  const bf16* pB = lB + (wn * 64 + fr) * 32 + fq * 8;

  f32x4 acc[4][4];
#pragma unroll
  for (int i = 0; i < 4; ++i)
#pragma unroll
    for (int j = 0; j < 4; ++j)
#pragma unroll
      for (int k = 0; k < 4; ++k) acc[i][j][k] = 0.f;

  for (int kt = 0; kt < D_MODEL / 32; ++kt) {
    cp16(dA0, srcA0); cp16(dA1, srcA1);
    cp16(dB0, srcB0); cp16(dB1, srcB1);
    srcA0 += 32; srcA1 += 32; srcB0 += 32; srcB1 += 32;
    __syncthreads();
    bf16x8 a[4];
#pragma unroll
    for (int fm = 0; fm < 4; ++fm) a[fm] = *(const bf16x8*)(pA + fm * 16 * 32);
#pragma unroll
    for (int fn = 0; fn < 4; ++fn) {
      bf16x8 b = *(const bf16x8*)(pB + fn * 16 * 32);
#pragma unroll
      for (int fm = 0; fm < 4; ++fm) acc[fm][fn] = mfma16(a[fm], b, acc[fm][fn]);
    }
    __syncthreads();
  }

  const int hbase = offsets[e] + row0;
#pragma unroll
  for (int fm = 0; fm < 4; ++fm) {
#pragma unroll
    for (int fn = 0; fn < 4; ++fn) {
#pragma unroll
      for (int i = 0; i < 4; ++i) {
        int m = wm * 64 + fm * 16 + fq * 4 + i;   // C/D: row = quad*4+reg
        if (row0 + m < cnt) {
          int col = c0 + wn * 64 + fn * 16 + fr;  // C/D: col = lane&15
          GU[(size_t)(hbase + m) * D_GU + col] = (bf16)acc[fm][fn][i];
        }
      }
    }
  }
}

// ====== fused elementwise: SwiGLU on GU (blocks < 8192) || wd fp32->bf16 (blocks >= 8192) ======
__global__ __launch_bounds__(256) void swiglu_cvtwd_kernel(
    bf16* __restrict__ GU, const float* __restrict__ wd, bf16* __restrict__ wdb)
{
  if (blockIdx.x < 8192) {
    const int idx = blockIdx.x * 256 + threadIdx.x;   // 8192 rows x 256 col-groups
    const int row = idx >> 8;
    const int col = (idx & 255) * 8;
    bf16* g = GU + (size_t)row * D_GU + col;
    bf16x8 g8 = *(const bf16x8*)g;
    bf16x8 u8 = *(const bf16x8*)(g + D_FF);
    bf16x8 h;
#pragma unroll
    for (int j = 0; j < 8; ++j) {
      float u = (float)u8[j];
      float gg = (float)g8[j];
      h[j] = (bf16)(gg * u / (1.f + expf(-u)));
    }
    *(bf16x8*)g = h;
  } else {
    const int i = (blockIdx.x - 8192) * 256 + threadIdx.x;  // 2.097M items exactly
    const float4* s = (const float4*)wd + 2 * (size_t)i;
    ((bf16x8*)wdb)[i] = cvt8(s[0], s[1]);
  }
}

// ====== GEMM2: H(=GU gate half) @ Wd_b^T -> O fp32 rows (plain stores, no atomics) ======
__global__ __launch_bounds__(256, 2) void gemm2_kernel(
    const bf16* __restrict__ GU, const bf16* __restrict__ wdb,
    const int* __restrict__ counts, const int* __restrict__ offsets,
    float* __restrict__ O)
{
  const int e = blockIdx.z;
  const int cnt = counts[e];
  const int row0 = blockIdx.y * 128;
  if (row0 >= cnt) return;
  const int c0 = blockIdx.x * 128;
  const int base = offsets[e];

  __shared__ bf16 lA[128 * 32];
  __shared__ bf16 lB[128 * 32];

  const int tid  = threadIdx.x;
  const int lane = tid & 63;
  const int wave = tid >> 6;
  const int l4 = lane >> 2;
  const int kb = (lane & 3) * 8;

  const int ra0 = wave * 16 + l4;
  const int ra1 = (wave + 4) * 16 + l4;
  const int m0 = min(row0 + ra0, cnt - 1);
  const int m1 = min(row0 + ra1, cnt - 1);
  const bf16* srcA0 = GU + (size_t)(base + m0) * D_GU + kb;   // gate half, pitch 4096
  const bf16* srcA1 = GU + (size_t)(base + m1) * D_GU + kb;
  const bf16* wde = wdb + (size_t)e * D_MODEL * D_FF;
  const bf16* srcB0 = wde + (size_t)(c0 + ra0) * D_FF + kb;
  const bf16* srcB1 = wde + (size_t)(c0 + ra1) * D_FF + kb;

  char* dA0 = (char*)lA + wave * 1024;
  char* dA1 = (char*)lA + (wave + 4) * 1024;
  char* dB0 = (char*)lB + wave * 1024;
  char* dB1 = (char*)lB + (wave + 4) * 1024;

  const int wm = wave >> 1;
  const int wn = wave & 1;
  const int fr = lane & 15;
  const int fq = lane >> 4;
  const bf16* pA = lA + (wm * 64 + fr) * 32 + fq * 8;
  const bf16* pB = lB + (wn * 64 + fr) * 32 + fq * 8;

  f32x4 acc[4][4];
#pragma unroll
  for (int i = 0; i < 4; ++i)
#pragma unroll
    for (int j = 0; j < 4; ++j)
#pragma unroll
      for (int k = 0; k < 4; ++k) acc[i][j][k] = 0.f;

  for (int kt = 0; kt < D_FF / 32; ++kt) {
    cp16(dA0, srcA0); cp16(dA1, srcA1);
    cp16(dB0, srcB0); cp16(dB1, srcB1);
    srcA0 += 32; srcA1 += 32; srcB0 += 32; srcB1 += 32;
    __syncthreads();
    bf16x8 a[4];
#pragma unroll
    for (int fm = 0; fm < 4; ++fm) a[fm] = *(const bf16x8*)(pA + fm * 16 * 32);
#pragma unroll
    for (int fn = 0; fn < 4; ++fn) {
      bf16x8 b = *(const bf16x8*)(pB + fn * 16 * 32);
#pragma unroll
      for (int fm = 0; fm < 4; ++fm) acc[fm][fn] = mfma16(a[fm], b, acc[fm][fn]);
    }
    __syncthreads();
  }

#pragma unroll
  for (int fm = 0; fm < 4; ++fm) {
#pragma unroll
    for (int i = 0; i < 4; ++i) {
      int m = wm * 64 + fm * 16 + fq * 4 + i;
      if (row0 + m < cnt) {
        float* orow = O + (size_t)(base + row0 + m) * D_MODEL;
#pragma unroll
        for (int fn = 0; fn < 4; ++fn) {
          int col = c0 + wn * 64 + fn * 16 + fr;
          orow[col] = acc[fm][fn][i];
        }
      }
    }
  }
}

// ====== combine: out[t] = p0*O[s0] + p1*O[s1]  (fp32, fully overwrites out) ======
__global__ __launch_bounds__(256) void combine_kernel(
    const float* __restrict__ O, const float2* __restrict__ meta_p,
    const int* __restrict__ tokslot, float* __restrict__ out)
{
  const int t = blockIdx.x;
  const float2 p = meta_p[t];
  const int s0 = tokslot[2 * t];
  const int s1 = tokslot[2 * t + 1];
  const int i = threadIdx.x;                       // 256 x float4 = 1024 cols
  const float4 a = ((const float4*)(O + (size_t)s0 * D_MODEL))[i];
  const float4 b = ((const float4*)(O + (size_t)s1 * D_MODEL))[i];
  float4 r;
  r.x = p.x * a.x + p.y * b.x;
  r.y = p.x * a.y + p.y * b.y;
  r.z = p.x * a.z + p.y * b.z;
  r.w = p.x * a.w + p.y * b.w;
  ((float4*)(out + (size_t)t * D_MODEL))[i] = r;
}

// =========================================================================================
extern "C" void kernel_launch(void* const* d_in, const int* in_sizes, int n_in,
                              void* d_out, int out_size, void* d_ws, size_t ws_size,
                              hipStream_t stream) {
  const float* x   = (const float*)d_in[0];
  const float* wr  = (const float*)d_in[1];
  const float* wgu = (const float*)d_in[2];
  const float* wd  = (const float*)d_in[3];
  float* out = (float*)d_out;

  char* ws = (char*)d_ws;
  // workspace layout — 136.5 MB total (same NEED as proven in rounds 4/5)
  int*    counts  = (int*)ws;                        // 32 B
  int*    offsets = (int*)(ws + 64);                 // 32 B
  int*    meta_e  = (int*)(ws + 1024);               // 16 KB
  float2* meta_p  = (float2*)(ws + 32768);           // 32 KB
  int*    tokslot = (int*)(ws + 65536);              // 32 KB
  int*    ids     = (int*)(ws + 131072);             // 128 KB
  float*  wts     = (float*)(ws + 262144);           // 128 KB
  bf16*   xb      = (bf16*)(ws + 524288);            // 8 MB
  bf16*   wgub    = (bf16*)(ws + 524288 + 8388608);  // 64 MB (dead after gemm1a)
  bf16*   wdb     = wgub;                            // 32 MB alias
  float*  O       = (float*)((char*)wgub + 33554432);// 32 MB alias (8192 x 1024 fp32)
  bf16*   GU      = (bf16*)(ws + 524288 + 8388608 + 67108864);  // 64 MB

  router_kernel<<<N_TOK / 32, 256, 0, stream>>>(x, wr, meta_e, meta_p, xb);
  compact_cvt_kernel<<<2049, 512, 0, stream>>>(
      meta_e, meta_p, counts, offsets, ids, wts, tokslot, wgu, wgub);
  gemm1a_kernel<<<dim3(D_GU / 128, N_TOK / 128, N_EXP), 256, 0, stream>>>(
      xb, wgub, counts, offsets, ids, GU);
  swiglu_cvtwd_kernel<<<16384, 256, 0, stream>>>(GU, wd, wdb);
  gemm2_kernel<<<dim3(D_MODEL / 128, N_TOK / 128, N_EXP), 256, 0, stream>>>(
      GU, wdb, counts, offsets, O);
  combine_kernel<<<N_TOK, 256, 0, stream>>>(O, meta_p, tokslot, out);
}